// Round 5
// baseline (364.489 us; speedup 1.0000x reference)
//
#include <hip/hip_runtime.h>
#include <hip/hip_fp16.h>
#include <math.h>

// Problem constants (from reference setup_inputs)
#define NN 100000
#define EE 1600000
constexpr int IN_F = 256, HID = 128, OUT_F = 64;

// CSR bucket-sort geometry
#define NB 196      // ceil(NN/512) coarse buckets (dst>>9)
#define CAP 16384   // per-bucket record capacity (avg 8192)
#define CH 16384    // edges per binning chunk
#define NCHUNK 98   // ceil(EE/CH)

typedef __bf16 bf16x8 __attribute__((ext_vector_type(8)));
typedef float  f32x4  __attribute__((ext_vector_type(4)));

__device__ __forceinline__ f32x4 mfma16(bf16x8 a, bf16x8 b, f32x4 c){
  return __builtin_amdgcn_mfma_f32_16x16x32_bf16(a, b, c, 0, 0, 0);
}

// ---------------- wave reductions ----------------
__device__ __forceinline__ float wred_max(float v){
#pragma unroll
  for (int m=1; m<64; m<<=1) v = fmaxf(v, __shfl_xor(v, m, 64));
  return v;
}
__device__ __forceinline__ float wred_sum(float v){
#pragma unroll
  for (int m=1; m<64; m<<=1) v += __shfl_xor(v, m, 64);
  return v;
}

// ---------------- CSR build, pass 1: bucket binning ----------------
__global__ __launch_bounds__(256) void k_bin(const int* __restrict__ src,
    const int* __restrict__ dst, int* __restrict__ bucketCnt, int* __restrict__ recs)
{
  __shared__ int sd[CH];          // staged dst (64 KB)
  __shared__ int cnt[NB];
  __shared__ int base[NB];
  const int tid = threadIdx.x;
  const int e0 = blockIdx.x * CH;
  const int ne = min(CH, EE - e0);

  for (int i=tid; i<NB; i+=256) cnt[i] = 0;
  __syncthreads();
  for (int i=tid; i<ne; i+=256){
    int d = dst[e0+i];
    sd[i] = d;
    atomicAdd(&cnt[d>>9], 1);
  }
  __syncthreads();
  for (int i=tid; i<NB; i+=256) base[i] = atomicAdd(&bucketCnt[i], cnt[i]);
  __syncthreads();
  for (int i=tid; i<NB; i+=256) cnt[i] = 0;
  __syncthreads();
  for (int i=tid; i<ne; i+=256){
    int d = sd[i], b = d >> 9;
    int r = atomicAdd(&cnt[b], 1);
    int pos = base[b] + r;
    if (pos < CAP) recs[(size_t)b*CAP + pos] = src[e0+i] | ((d & 511) << 17);
  }
}

__global__ void k_bscan(const int* __restrict__ bucketCnt, int* __restrict__ bucketStart){
  __shared__ int sd[256];
  int t = threadIdx.x;
  int v = (t < NB) ? min(bucketCnt[t], CAP) : 0;
  sd[t] = v; __syncthreads();
#pragma unroll
  for (int off=1; off<256; off<<=1){
    int x = (t >= off) ? sd[t-off] : 0;
    __syncthreads();
    sd[t] += x;
    __syncthreads();
  }
  if (t < NB) bucketStart[t] = sd[t] - v;
}

// ---------------- CSR build, pass 2: per-bucket finalize ----------------
__global__ __launch_bounds__(256) void k_csr(const int* __restrict__ recs,
    const int* __restrict__ bucketCnt, const int* __restrict__ bucketStart,
    int* __restrict__ rp, int* __restrict__ colsrc)
{
  __shared__ int hist[513];
  __shared__ int srcbuf[CAP];     // 64 KB
  const int tid = threadIdx.x;
  const int b = blockIdx.x;
  const int cntb = min(bucketCnt[b], CAP);
  const int bstart = bucketStart[b];
  const int n0 = b << 9;
  const int nnode = min(512, NN - n0);
  const int* rb = recs + (size_t)b*CAP;

  for (int i=tid; i<513; i+=256) hist[i] = 0;
  __syncthreads();
  for (int i=tid; i<cntb; i+=256) atomicAdd(&hist[(rb[i] >> 17) + 1], 1);
  __syncthreads();
#pragma unroll
  for (int off=1; off<513; off<<=1){
    int vals[3];
    int q = 0;
    for (int i=tid; i<513; i+=256, q++) vals[q] = (i >= off) ? hist[i-off] : 0;
    __syncthreads();
    q = 0;
    for (int i=tid; i<513; i+=256, q++) hist[i] += vals[q];
    __syncthreads();
  }
  for (int l=tid; l<nnode; l+=256) rp[n0+l] = bstart + hist[l];
  if (b == 0 && tid == 0) rp[NN] = EE;
  __syncthreads();
  for (int i=tid; i<cntb; i+=256){
    int rec = rb[i];
    int r = atomicAdd(&hist[rec >> 17], 1);
    srcbuf[r] = rec & 0x1FFFF;
  }
  __syncthreads();
  for (int i=tid; i<cntb; i+=256) colsrc[bstart + i] = srcbuf[i];
}

// ---------------- weight pre-split: W[K][N] f32 -> Wt_hi/Wt_lo [N][K] bf16 ----------------
__global__ void k_wsplit(const float* __restrict__ W, __bf16* __restrict__ hi, __bf16* __restrict__ lo,
                         int K, int N){
  int idx = blockIdx.x*256 + threadIdx.x;
  if (idx >= K*N) return;
  int k = idx / N, n = idx - k*N;
  float v = W[idx];
  __bf16 h = (__bf16)v;
  hi[(size_t)n*K + k] = h;
  lo[(size_t)n*K + k] = (__bf16)(v - (float)h);
}

// ---------------- split-bf16 MFMA GEMM ----------------
// C[rows,BN] = A[rows,K] @ W[K,BN] (+bias, +att dots)
// A: f32 (ASPLIT=false, converted at staging) or pre-split hi/lo bf16 planes (ASPLIT=true).
// Block: 256 thr = 4 waves, 128 rows/block; wave w owns rows w*32..w*32+31, full BN.
// OMODE: 0=f32 out, 1=fp16 out, 2=split hi/lo bf16 out.
template<int K, int BN, bool ATT, bool BIAS, bool ASPLIT, int OMODE>
__global__ __launch_bounds__(256) void k_gemm_mfma(
    const float* __restrict__ Af, const __bf16* __restrict__ AhiG, const __bf16* __restrict__ AloG,
    const __bf16* __restrict__ Bhi, const __bf16* __restrict__ Blo,
    const float* __restrict__ bias,
    void* __restrict__ C0, void* __restrict__ C1,
    const float* __restrict__ attS, const float* __restrict__ attD,
    float* __restrict__ asrc, float* __restrict__ adst, int nrows)
{
  constexpr int NF = BN/16;
  __shared__ __bf16 Ah[128][40];    // 80B rows -> <=2-way banks
  __shared__ __bf16 Al[128][40];
  __shared__ __bf16 Bh[BN][56];     // 112B rows -> <=2-way
  __shared__ __bf16 Bl[BN][56];
  const int tid = threadIdx.x;
  const int w = tid >> 6, lane = tid & 63;
  const int lr = lane & 15, lk = (lane >> 4) * 8;
  const int rowBase = blockIdx.x * 128;

  f32x4 acc[2][NF];
#pragma unroll
  for (int f=0; f<2; f++)
#pragma unroll
    for (int nf=0; nf<NF; nf++) acc[f][nf] = (f32x4)(0.f);

  const int ar = tid >> 1, ah2 = (tid & 1) * 16;   // A: row ar, 16 elems at ah2
  int agr = rowBase + ar; if (agr >= nrows) agr = nrows - 1;
  const int bn = tid >> 1, bh2 = (tid & 1) * 16;
  const bool bact = tid < BN*2;

  for (int kc=0; kc<K; kc+=32){
    bf16x8 wh0, wh1, wl0, wl1;
    if constexpr (ASPLIT){
      const __bf16* ph = AhiG + (size_t)agr*K + kc + ah2;
      const __bf16* pl = AloG + (size_t)agr*K + kc + ah2;
      wh0 = *(const bf16x8*)ph;     wh1 = *(const bf16x8*)(ph + 8);
      wl0 = *(const bf16x8*)pl;     wl1 = *(const bf16x8*)(pl + 8);
    } else {
      const float* pa = Af + (size_t)agr*K + kc + ah2;
      float4 f0 = *(const float4*)pa,       f1 = *(const float4*)(pa + 4);
      float4 f2 = *(const float4*)(pa + 8), f3 = *(const float4*)(pa + 12);
      float fv[16] = {f0.x,f0.y,f0.z,f0.w, f1.x,f1.y,f1.z,f1.w,
                      f2.x,f2.y,f2.z,f2.w, f3.x,f3.y,f3.z,f3.w};
#pragma unroll
      for (int u=0; u<8; u++){
        __bf16 h = (__bf16)fv[u];
        wh0[u] = h; wl0[u] = (__bf16)(fv[u] - (float)h);
      }
#pragma unroll
      for (int u=0; u<8; u++){
        __bf16 h = (__bf16)fv[8+u];
        wh1[u] = h; wl1[u] = (__bf16)(fv[8+u] - (float)h);
      }
    }
    bf16x8 vb0, vb1, vc0, vc1;
    if (bact){
      const __bf16* ph = Bhi + (size_t)bn*K + kc + bh2;
      const __bf16* pl = Blo + (size_t)bn*K + kc + bh2;
      vb0 = *(const bf16x8*)ph;  vb1 = *(const bf16x8*)(ph + 8);
      vc0 = *(const bf16x8*)pl;  vc1 = *(const bf16x8*)(pl + 8);
    }
    __syncthreads();   // previous iter's LDS reads done
    *(bf16x8*)&Ah[ar][ah2]     = wh0;  *(bf16x8*)&Ah[ar][ah2 + 8] = wh1;
    *(bf16x8*)&Al[ar][ah2]     = wl0;  *(bf16x8*)&Al[ar][ah2 + 8] = wl1;
    if (bact){
      *(bf16x8*)&Bh[bn][bh2]     = vb0;  *(bf16x8*)&Bh[bn][bh2 + 8] = vb1;
      *(bf16x8*)&Bl[bn][bh2]     = vc0;  *(bf16x8*)&Bl[bn][bh2 + 8] = vc1;
    }
    __syncthreads();

    bf16x8 fah0 = *(const bf16x8*)&Ah[w*32 + lr][lk];
    bf16x8 fah1 = *(const bf16x8*)&Ah[w*32 + 16 + lr][lk];
    bf16x8 fal0 = *(const bf16x8*)&Al[w*32 + lr][lk];
    bf16x8 fal1 = *(const bf16x8*)&Al[w*32 + 16 + lr][lk];
#pragma unroll
    for (int nf=0; nf<NF; nf++){
      bf16x8 bh = *(const bf16x8*)&Bh[nf*16 + lr][lk];
      acc[0][nf] = mfma16(fah0, bh, acc[0][nf]);
      acc[1][nf] = mfma16(fah1, bh, acc[1][nf]);
      acc[0][nf] = mfma16(fal0, bh, acc[0][nf]);
      acc[1][nf] = mfma16(fal1, bh, acc[1][nf]);
    }
#pragma unroll
    for (int nf=0; nf<NF; nf++){
      bf16x8 bl = *(const bf16x8*)&Bl[nf*16 + lr][lk];
      acc[0][nf] = mfma16(fah0, bl, acc[0][nf]);
      acc[1][nf] = mfma16(fah1, bl, acc[1][nf]);
    }
  }

  // epilogue: C/D layout col=lane&15, row=(lane>>4)*4+reg  [m89]
  const int rq = lane >> 4;
#pragma unroll
  for (int f=0; f<2; f++){
    const int rbase = rowBase + w*32 + f*16 + rq*4;
    if (ATT){
      float ps[4] = {0.f,0.f,0.f,0.f}, pd[4] = {0.f,0.f,0.f,0.f};
#pragma unroll
      for (int nf=0; nf<NF; nf++){
        float sv = attS[nf*16 + lr], dv = attD[nf*16 + lr];
#pragma unroll
        for (int i=0;i<4;i++){
          ps[i] = fmaf(acc[f][nf][i], sv, ps[i]);
          pd[i] = fmaf(acc[f][nf][i], dv, pd[i]);
        }
      }
#pragma unroll
      for (int mm=1; mm<16; mm<<=1){
#pragma unroll
        for (int i=0;i<4;i++){
          ps[i] += __shfl_xor(ps[i], mm, 64);
          pd[i] += __shfl_xor(pd[i], mm, 64);
        }
      }
      if (lr == 0){
#pragma unroll
        for (int i=0;i<4;i++){
          int row = rbase + i;
          if (row < nrows){ asrc[row] = ps[i]; adst[row] = pd[i]; }
        }
      }
    }
#pragma unroll
    for (int i=0;i<4;i++){
      int row = rbase + i;
      if (row < nrows){
#pragma unroll
        for (int nf=0; nf<NF; nf++){
          float v = acc[f][nf][i] + (BIAS ? bias[nf*16 + lr] : 0.f);
          size_t cidx = (size_t)row*BN + nf*16 + lr;
          if constexpr (OMODE == 0){
            ((float*)C0)[cidx] = v;
          } else if constexpr (OMODE == 1){
            ((__half*)C0)[cidx] = __float2half(v);
          } else {
            __bf16 h = (__bf16)v;
            ((__bf16*)C0)[cidx] = h;
            ((__bf16*)C1)[cidx] = (__bf16)(v - (float)h);
          }
        }
      }
    }
  }
}

// ---------------- GAT aggregation: one wave per dst node ----------------
// 4 edges per step; lane = 16*eg + cl: edge subgroup eg (0..3), channel chunk cl (0..15, 8 ch each).
// g fp16 [N][128]; output written as split hi/lo bf16 planes (relu'd).
__global__ __launch_bounds__(256) void k_agg(const __half* __restrict__ g,
    const float* __restrict__ asrc, const float* __restrict__ adst,
    const int* __restrict__ rp, const int* __restrict__ cs,
    const float* __restrict__ bias, __bf16* __restrict__ outHi, __bf16* __restrict__ outLo)
{
  int w = threadIdx.x >> 6, lane = threadIdx.x & 63;
  int node = blockIdx.x*4 + w;
  if (node >= NN) return;
  int r0 = rp[node], deg = rp[node+1] - r0;
  float ad = adst[node];
  const int eg = lane >> 4, cl = lane & 15;

  float m = -INFINITY, ssum = 0.f;
  float a[8] = {0.f,0.f,0.f,0.f,0.f,0.f,0.f,0.f};

  for (int base=0; base<deg; base+=64){
    int i = base + lane;
    bool val = i < deg;
    int sj = val ? cs[r0+i] : 0;
    float e = -INFINITY;
    if (val){ float t = asrc[sj] + ad; e = (t > 0.f) ? t : 0.2f*t; }
    float mn = fmaxf(m, wred_max(e));
    float sc = __expf(m - mn);            // m=-inf on first chunk -> 0
    float p = val ? __expf(e - mn) : 0.f;
    float psum = wred_sum(p);
    ssum = ssum*sc + psum;
#pragma unroll
    for (int u=0;u<8;u++) a[u] *= sc;

    int cnt = min(deg - base, 64);
    int steps = (cnt + 3) >> 2;
    // pipelined: one gather in flight ahead
    int idx = eg;
    float al = __shfl(p,  idx, 64);
    int   s  = __shfl(sj, idx, 64);
    float4 raw = *(const float4*)(g + s*HID + cl*8);
    for (int j=0; j<steps; j++){
      float4 curv = raw; float alc = al;
      if (j+1 < steps){
        idx = 4*(j+1) + eg;
        al = __shfl(p,  idx, 64);
        s  = __shfl(sj, idx, 64);
        raw = *(const float4*)(g + s*HID + cl*8);
      }
      const __half2* hp = (const __half2*)&curv;
#pragma unroll
      for (int u=0;u<4;u++){
        float2 fv = __half22float2(hp[u]);
        a[2*u]   = fmaf(alc, fv.x, a[2*u]);
        a[2*u+1] = fmaf(alc, fv.y, a[2*u+1]);
      }
    }
    m = mn;
  }
  // reduce across the 4 edge subgroups (lanes lane^16, lane^32)
#pragma unroll
  for (int u=0;u<8;u++){
    a[u] += __shfl_xor(a[u], 16, 64);
    a[u] += __shfl_xor(a[u], 32, 64);
  }
  if (eg == 0){
    float inv = 1.f/(ssum + 1e-16f);
    bf16x8 hv, lv;
#pragma unroll
    for (int u=0;u<8;u++){
      float o = fmaxf(a[u]*inv + bias[cl*8 + u], 0.f);
      __bf16 h = (__bf16)o;
      hv[u] = h;
      lv[u] = (__bf16)(o - (float)h);
    }
    *(bf16x8*)(outHi + (size_t)node*HID + cl*8) = hv;
    *(bf16x8*)(outLo + (size_t)node*HID + cl*8) = lv;
  }
}

// ---------------- host ----------------
extern "C" void kernel_launch(void* const* d_in, const int* in_sizes, int n_in,
                              void* d_out, int out_size, void* d_ws, size_t ws_size,
                              hipStream_t stream) {
  const float* x     = (const float*)d_in[0];
  const int*   ei    = (const int*)  d_in[1];
  const float* W_in  = (const float*)d_in[2];
  const float* b_in  = (const float*)d_in[3];
  const float* W1    = (const float*)d_in[4];
  const float* as1   = (const float*)d_in[5];
  const float* ad1   = (const float*)d_in[6];
  const float* bias1 = (const float*)d_in[7];
  const float* W2    = (const float*)d_in[8];
  const float* as2   = (const float*)d_in[9];
  const float* ad2   = (const float*)d_in[10];
  const float* bias2 = (const float*)d_in[11];
  const float* W_out = (const float*)d_in[12];
  const float* b_out = (const float*)d_in[13];
  float* out = (float*)d_out;

  char* ws = (char*)d_ws;
  size_t off = 0;
  auto alloc = [&](size_t bytes)->void*{ void* p = ws + off; off += (bytes + 255) & ~255ull; return p; };
  __bf16* Hhi  = (__bf16*)alloc((size_t)NN*HID*2);   // h; later o2
  __bf16* Hlo  = (__bf16*)alloc((size_t)NN*HID*2);
  __half* G    = (__half*)alloc((size_t)NN*HID*2);   // g (both layers)
  __bf16* Ohi  = (__bf16*)alloc((size_t)NN*HID*2);   // o1
  __bf16* Olo  = (__bf16*)alloc((size_t)NN*HID*2);
  float*  asrc = (float*) alloc((size_t)NN*4);
  float*  adst = (float*) alloc((size_t)NN*4);
  int*    rp   = (int*)   alloc((size_t)(NN+1)*4);
  int*    colsrc = (int*) alloc((size_t)EE*4);
  int*    recs   = (int*) alloc((size_t)NB*CAP*4);   // 12.85 MB
  int*    bucketCnt   = (int*)alloc(NB*4);
  int*    bucketStart = (int*)alloc(NB*4);
  __bf16* whiI = (__bf16*)alloc((size_t)HID*IN_F*2);
  __bf16* wloI = (__bf16*)alloc((size_t)HID*IN_F*2);
  __bf16* whi1 = (__bf16*)alloc((size_t)HID*HID*2);
  __bf16* wlo1 = (__bf16*)alloc((size_t)HID*HID*2);
  __bf16* whi2 = (__bf16*)alloc((size_t)HID*HID*2);
  __bf16* wlo2 = (__bf16*)alloc((size_t)HID*HID*2);
  __bf16* whiO = (__bf16*)alloc((size_t)OUT_F*HID*2);
  __bf16* wloO = (__bf16*)alloc((size_t)OUT_F*HID*2);
  (void)ws_size; (void)in_sizes; (void)n_in; (void)out_size;

  const int* srcIdx = ei;        // edge_index[0]
  const int* dstIdx = ei + EE;   // edge_index[1]

  // weight pre-split (tiny)
  k_wsplit<<<(IN_F*HID+255)/256, 256, 0, stream>>>(W_in,  whiI, wloI, IN_F, HID);
  k_wsplit<<<(HID*HID+255)/256, 256, 0, stream>>>(W1,    whi1, wlo1, HID, HID);
  k_wsplit<<<(HID*HID+255)/256, 256, 0, stream>>>(W2,    whi2, wlo2, HID, HID);
  k_wsplit<<<(HID*OUT_F+255)/256, 256, 0, stream>>>(W_out, whiO, wloO, HID, OUT_F);

  // CSR by dst: 2-pass bucket sort
  hipMemsetAsync(bucketCnt, 0, NB*4, stream);
  k_bin  <<<NCHUNK, 256, 0, stream>>>(srcIdx, dstIdx, bucketCnt, recs);
  k_bscan<<<1, 256, 0, stream>>>(bucketCnt, bucketStart);
  k_csr  <<<NB, 256, 0, stream>>>(recs, bucketCnt, bucketStart, rp, colsrc);

  const int gblocks = (NN + 127) / 128;
  // h = x @ W_in + b_in  -> split bf16
  k_gemm_mfma<256,128,false,true,false,2><<<gblocks, 256, 0, stream>>>(
      x, nullptr, nullptr, whiI, wloI, b_in, Hhi, Hlo, nullptr, nullptr, nullptr, nullptr, NN);
  // layer 1: g = h @ W1 (+att dots) -> fp16
  k_gemm_mfma<128,128,true,false,true,1><<<gblocks, 256, 0, stream>>>(
      nullptr, Hhi, Hlo, whi1, wlo1, nullptr, G, nullptr, as1, ad1, asrc, adst, NN);
  k_agg<<<NN/4, 256, 0, stream>>>(G, asrc, adst, rp, colsrc, bias1, Ohi, Olo);
  // layer 2
  k_gemm_mfma<128,128,true,false,true,1><<<gblocks, 256, 0, stream>>>(
      nullptr, Ohi, Olo, whi2, wlo2, nullptr, G, nullptr, as2, ad2, asrc, adst, NN);
  k_agg<<<NN/4, 256, 0, stream>>>(G, asrc, adst, rp, colsrc, bias2, Hhi, Hlo);
  // out = o2 @ W_out + b_out -> f32
  k_gemm_mfma<128,64,false,true,true,0><<<gblocks, 256, 0, stream>>>(
      nullptr, Hhi, Hlo, whiO, wloO, b_out, out, nullptr, nullptr, nullptr, nullptr, nullptr, NN);
}